// Round 1
// baseline (67.609 us; speedup 1.0000x reference)
//
#include <hip/hip_runtime.h>
#include <math.h>
#include <stdint.h>

#define NROWS 1024
#define DCAT  16384
#define BLK   256
#define NNEG  48
#define CAP   512
// Candidate threshold on rank = bits>>9 (23-bit). P(pass) = 98304/2^23 = 1.17%.
// E[cands/row] ~= 192, sd ~= 13.8 -> P(<48 cands) and P(>512 cands) are ~0.
#define RANK_THR (8388608u - 98304u)

__device__ __forceinline__ uint32_t rotl_(uint32_t x, int r) {
  return (x << r) | (x >> (32 - r));
}

// JAX threefry2x32, key = (0, 42) [jax.random.key(42)], counter = (0, idx).
// Returns out0 ^ out1 (jax_threefry_partitionable 32-bit random-bits path).
__device__ __forceinline__ uint32_t tf_bits(uint32_t idx) {
  const uint32_t ks0 = 0u, ks1 = 42u, ks2 = 0x1BD11BF0u; // 0x1BD11BDA ^ 0 ^ 42
  uint32_t x0 = ks0;        // counter_hi + ks0
  uint32_t x1 = idx + ks1;  // counter_lo + ks1
#define QR4(a,b,c,d) \
  x0 += x1; x1 = rotl_(x1,(a)); x1 ^= x0; \
  x0 += x1; x1 = rotl_(x1,(b)); x1 ^= x0; \
  x0 += x1; x1 = rotl_(x1,(c)); x1 ^= x0; \
  x0 += x1; x1 = rotl_(x1,(d)); x1 ^= x0;
  QR4(13,15,26,6)  x0 += ks1; x1 += ks2 + 1u;
  QR4(17,29,16,24) x0 += ks2; x1 += ks0 + 2u;
  QR4(13,15,26,6)  x0 += ks0; x1 += ks1 + 3u;
  QR4(17,29,16,24) x0 += ks1; x1 += ks2 + 4u;
  QR4(13,15,26,6)  x0 += ks2; x1 += ks0 + 5u;
#undef QR4
  return x0 ^ x1;
}

// jax.nn.softplus = logaddexp(x, 0) = max(x,0) + log1p(exp(-|x|))
__device__ __forceinline__ float softplus_(float x) {
  return fmaxf(x, 0.f) + log1pf(expf(-fabsf(x)));
}

__global__ __launch_bounds__(BLK) void t2l2_kernel(
    const float* __restrict__ pred, const float* __restrict__ target,
    float* __restrict__ out) {
  const int row = blockIdx.x;
  const int tid = threadIdx.x;
  const float* __restrict__ trow = target + (size_t)row * DCAT;
  const float* __restrict__ prow = pred + (size_t)row * DCAT;

  __shared__ unsigned long long ckeys[CAP];
  __shared__ int cnt_s;
  __shared__ float wsum[BLK / 64];
  if (tid == 0) cnt_s = 0;
  __syncthreads();

  float acc = 0.f;
  const uint32_t base = (uint32_t)row * (uint32_t)DCAT;

  // Phase 1: stream target (float4), threefry rank per element,
  // positives -> pos loss; high-rank non-positives -> LDS candidate list.
  for (int it = 0; it < DCAT / (BLK * 4); ++it) {
    const int c = it * (BLK * 4) + tid * 4;
    const float4 t4 = *reinterpret_cast<const float4*>(trow + c);
    #pragma unroll
    for (int j = 0; j < 4; ++j) {
      const int col = c + j;
      const float tv = (j == 0) ? t4.x : (j == 1) ? t4.y : (j == 2) ? t4.z : t4.w;
      const uint32_t bits = tf_bits(base + (uint32_t)col);
      const uint32_t rank = bits >> 9;  // monotone in uniform value
      if (tv > 0.f) {
        acc += softplus_(-prow[col]);   // positive term: softplus(-x)
      } else if (rank >= RANK_THR) {
        const int p = atomicAdd(&cnt_s, 1);
        if (p < CAP)
          // key: (rank desc, col asc) via single u64 compare; unique per row
          ckeys[p] = ((unsigned long long)rank << 14)
                   | (unsigned long long)(DCAT - 1 - col);
      }
    }
  }
  __syncthreads();

  // Phase 2: exact top-48 among M~192 candidates by rank-counting (O(M^2),
  // broadcast LDS reads). Order-independent -> deterministic selection.
  const int M = min(cnt_s, CAP);
  for (int i = tid; i < M; i += BLK) {
    const unsigned long long mine = ckeys[i];
    int higher = 0;
    for (int j = 0; j < M; ++j) higher += (ckeys[j] > mine) ? 1 : 0;
    if (higher < NNEG) {
      const int col = DCAT - 1 - (int)(mine & 0x3FFFull);
      acc += softplus_(prow[col]);      // negative term: softplus(x)
    }
  }

  // Block reduction -> one atomic per block.
  for (int off = 32; off > 0; off >>= 1) acc += __shfl_down(acc, off, 64);
  if ((tid & 63) == 0) wsum[tid >> 6] = acc;
  __syncthreads();
  if (tid == 0)
    atomicAdd(out, wsum[0] + wsum[1] + wsum[2] + wsum[3]);
}

extern "C" void kernel_launch(void* const* d_in, const int* in_sizes, int n_in,
                              void* d_out, int out_size, void* d_ws, size_t ws_size,
                              hipStream_t stream) {
  const float* pred   = (const float*)d_in[0];
  const float* target = (const float*)d_in[1];
  // d_in[2] = k (int scalar) — compile-time constant 8 in this problem.
  float* out = (float*)d_out;
  hipMemsetAsync(out, 0, sizeof(float), stream);
  t2l2_kernel<<<dim3(NROWS), dim3(BLK), 0, stream>>>(pred, target, out);
}

// Round 2
// 52.179 us; speedup vs baseline: 1.2957x; 1.2957x over previous
//
#include <hip/hip_runtime.h>
#include <math.h>
#include <stdint.h>

#define NROWS 1024
#define DCAT  16384
#define BLK   512
#define NNEG  48
#define CAP   512
// Candidate threshold directly on the 32-bit threefry output:
// rank = bits>>9 >= 2^23 - 98304  <=>  bits >= 0xFD000000.
// P(pass) = 1.17%, E[cands/row] ~= 192, sd ~= 13.8 -> P(<48) ~ P(>512) ~ 0.
#define BITS_THR 0xFD000000u

__device__ __forceinline__ uint32_t rotl_(uint32_t x, int r) {
  return (x << r) | (x >> (32 - r));
}

// JAX threefry2x32, key=(0,42), counter=(0,idx), out = x0^x1 (partitionable
// 32-bit path). 4 independent chains interleaved for ILP.
__device__ __forceinline__ void tf_bits4(uint32_t base_idx, uint32_t out[4]) {
  const uint32_t ks0 = 0u, ks1 = 42u, ks2 = 0x1BD11BF0u; // 0x1BD11BDA^0^42
  uint32_t x0[4], x1[4];
  #pragma unroll
  for (int l = 0; l < 4; ++l) { x0[l] = ks0; x1[l] = base_idx + (uint32_t)l + ks1; }
#define QR(rot) \
  _Pragma("unroll") \
  for (int l = 0; l < 4; ++l) { x0[l] += x1[l]; x1[l] = rotl_(x1[l], rot); x1[l] ^= x0[l]; }
#define INJ(a, b, n) \
  _Pragma("unroll") \
  for (int l = 0; l < 4; ++l) { x0[l] += (a); x1[l] += (b) + (n); }
  QR(13) QR(15) QR(26) QR(6)  INJ(ks1, ks2, 1u)
  QR(17) QR(29) QR(16) QR(24) INJ(ks2, ks0, 2u)
  QR(13) QR(15) QR(26) QR(6)  INJ(ks0, ks1, 3u)
  QR(17) QR(29) QR(16) QR(24) INJ(ks1, ks2, 4u)
  QR(13) QR(15) QR(26) QR(6)  INJ(ks2, ks0, 5u)
#undef QR
#undef INJ
  #pragma unroll
  for (int l = 0; l < 4; ++l) out[l] = x0[l] ^ x1[l];
}

// jax.nn.softplus = max(x,0) + log1p(exp(-|x|))
__device__ __forceinline__ float softplus_(float x) {
  return fmaxf(x, 0.f) + log1pf(expf(-fabsf(x)));
}

__global__ __launch_bounds__(BLK) void t2l2_kernel(
    const float* __restrict__ pred, const float* __restrict__ target,
    float* __restrict__ out) {
  const int row = blockIdx.x;
  const int tid = threadIdx.x;
  const float* __restrict__ trow = target + (size_t)row * DCAT;
  const float* __restrict__ prow = pred + (size_t)row * DCAT;

  __shared__ unsigned long long ckeys[CAP];
  __shared__ int cnt_s;
  __shared__ float wsum[BLK / 64];
  if (tid == 0) cnt_s = 0;
  __syncthreads();

  float acc = 0.f;
  const uint32_t base = (uint32_t)row * (uint32_t)DCAT;

  // Phase 1: stream target (float4); 4-wide interleaved threefry;
  // positives -> pos loss; high-bits non-positives -> LDS candidate list.
  #pragma unroll
  for (int it = 0; it < DCAT / (BLK * 4); ++it) {
    const int c = it * (BLK * 4) + tid * 4;
    const float4 t4 = *reinterpret_cast<const float4*>(trow + c);
    uint32_t bits[4];
    tf_bits4(base + (uint32_t)c, bits);
    const float tv[4] = {t4.x, t4.y, t4.z, t4.w};
    #pragma unroll
    for (int j = 0; j < 4; ++j) {
      const int col = c + j;
      if (tv[j] > 0.f) {
        acc += softplus_(-prow[col]);     // positive term: softplus(-x)
      } else if (bits[j] >= BITS_THR) {
        const int p = atomicAdd(&cnt_s, 1);
        if (p < CAP)
          // key: (rank desc, col asc) via one u64 compare; unique per row
          ckeys[p] = ((unsigned long long)(bits[j] >> 9) << 14)
                   | (unsigned long long)(DCAT - 1 - col);
      }
    }
  }
  __syncthreads();

  // Phase 2: exact top-48 among M~192 candidates by rank-counting (O(M^2),
  // broadcast LDS reads). Order-independent -> deterministic.
  const int M = min(cnt_s, CAP);
  for (int i = tid; i < M; i += BLK) {
    const unsigned long long mine = ckeys[i];
    int higher = 0;
    for (int j = 0; j < M; ++j) higher += (ckeys[j] > mine) ? 1 : 0;
    if (higher < NNEG) {
      const int col = DCAT - 1 - (int)(mine & 0x3FFFull);
      acc += softplus_(prow[col]);        // negative term: softplus(x)
    }
  }

  // Block reduction -> one atomic per block.
  for (int off = 32; off > 0; off >>= 1) acc += __shfl_down(acc, off, 64);
  if ((tid & 63) == 0) wsum[tid >> 6] = acc;
  __syncthreads();
  if (tid == 0) {
    float s = 0.f;
    #pragma unroll
    for (int w = 0; w < BLK / 64; ++w) s += wsum[w];
    atomicAdd(out, s);
  }
}

extern "C" void kernel_launch(void* const* d_in, const int* in_sizes, int n_in,
                              void* d_out, int out_size, void* d_ws, size_t ws_size,
                              hipStream_t stream) {
  const float* pred   = (const float*)d_in[0];
  const float* target = (const float*)d_in[1];
  // d_in[2] = k (int scalar) — compile-time constant 8 in this problem.
  float* out = (float*)d_out;
  hipMemsetAsync(out, 0, sizeof(float), stream);
  t2l2_kernel<<<dim3(NROWS), dim3(BLK), 0, stream>>>(pred, target, out);
}

// Round 3
// 51.994 us; speedup vs baseline: 1.3003x; 1.0036x over previous
//
#include <hip/hip_runtime.h>
#include <math.h>
#include <stdint.h>

#define NROWS 1024
#define DCAT  16384
#define BLK   512
#define EPT   8                      // elements per thread per outer iter
#define NITER (DCAT / (BLK * EPT))   // = 4
#define NNEG  48
#define CAP   512
// Candidate threshold directly on the 32-bit threefry output:
// rank = bits>>9 >= 2^23 - 98304  <=>  bits >= 0xFD000000.
// P(pass) = 1.17%, E[cands/row] ~= 192, sd ~= 13.8 -> P(<48) ~ P(>512) ~ 0.
#define BITS_THR 0xFD000000u

__device__ __forceinline__ uint32_t rotl_(uint32_t x, int r) {
  return (x << r) | (x >> (32 - r));
}

// JAX threefry2x32, key=(0,42), counter=(0,idx), out = x0^x1 (partitionable
// 32-bit path). 8 independent chains interleaved for ILP.
__device__ __forceinline__ void tf_bits8(uint32_t base_idx, uint32_t out[EPT]) {
  const uint32_t ks0 = 0u, ks1 = 42u, ks2 = 0x1BD11BF0u; // 0x1BD11BDA^0^42
  uint32_t x0[EPT], x1[EPT];
  #pragma unroll
  for (int l = 0; l < EPT; ++l) { x0[l] = ks0; x1[l] = base_idx + (uint32_t)l + ks1; }
#define QR(rot) \
  _Pragma("unroll") \
  for (int l = 0; l < EPT; ++l) { x0[l] += x1[l]; x1[l] = rotl_(x1[l], rot); x1[l] ^= x0[l]; }
#define INJ(a, b, n) \
  _Pragma("unroll") \
  for (int l = 0; l < EPT; ++l) { x0[l] += (a); x1[l] += (b) + (n); }
  QR(13) QR(15) QR(26) QR(6)  INJ(ks1, ks2, 1u)
  QR(17) QR(29) QR(16) QR(24) INJ(ks2, ks0, 2u)
  QR(13) QR(15) QR(26) QR(6)  INJ(ks0, ks1, 3u)
  QR(17) QR(29) QR(16) QR(24) INJ(ks1, ks2, 4u)
  QR(13) QR(15) QR(26) QR(6)  INJ(ks2, ks0, 5u)
#undef QR
#undef INJ
  #pragma unroll
  for (int l = 0; l < EPT; ++l) out[l] = x0[l] ^ x1[l];
}

// jax.nn.softplus = max(x,0) + log1p(exp(-|x|))
__device__ __forceinline__ float softplus_(float x) {
  return fmaxf(x, 0.f) + log1pf(expf(-fabsf(x)));
}

__global__ __launch_bounds__(BLK) void t2l2_kernel(
    const float* __restrict__ pred, const float* __restrict__ target,
    float* __restrict__ out) {
  const int row = blockIdx.x;
  const int tid = threadIdx.x;
  const float* __restrict__ trow = target + (size_t)row * DCAT;
  const float* __restrict__ prow = pred + (size_t)row * DCAT;
  const float4* __restrict__ t4p = reinterpret_cast<const float4*>(trow);

  __shared__ unsigned long long ckeys[CAP];
  __shared__ int cnt_s;
  __shared__ float wsum[BLK / 64];
  if (tid == 0) cnt_s = 0;
  __syncthreads();

  float acc = 0.f;
  const uint32_t base = (uint32_t)row * (uint32_t)DCAT;

  // Phase 1: stream target as 2x float4 per thread per iter (full unroll ->
  // loads hoisted early, latency hidden under ~600 VALU/iter); 8-wide
  // interleaved threefry; positives -> pos loss; high-bits -> LDS cand list.
  #pragma unroll
  for (int it = 0; it < NITER; ++it) {
    const int c = it * (BLK * EPT) + tid * EPT;      // 8 consecutive elems
    const float4 a0 = t4p[c / 4];
    const float4 a1 = t4p[c / 4 + 1];
    uint32_t bits[EPT];
    tf_bits8(base + (uint32_t)c, bits);
    const float tv[EPT] = {a0.x, a0.y, a0.z, a0.w, a1.x, a1.y, a1.z, a1.w};
    #pragma unroll
    for (int j = 0; j < EPT; ++j) {
      const int col = c + j;
      if (tv[j] > 0.f) {
        acc += softplus_(-prow[col]);     // positive term: softplus(-x)
      } else if (bits[j] >= BITS_THR) {
        const int p = atomicAdd(&cnt_s, 1);
        if (p < CAP)
          // key: (rank desc, col asc) via one u64 compare; unique per row
          ckeys[p] = ((unsigned long long)(bits[j] >> 9) << 14)
                   | (unsigned long long)(DCAT - 1 - col);
      }
    }
  }
  __syncthreads();

  // Phase 2: exact top-48 among M~192 candidates by rank-counting (O(M^2),
  // broadcast LDS reads). Order-independent -> deterministic.
  const int M = min(cnt_s, CAP);
  for (int i = tid; i < M; i += BLK) {
    const unsigned long long mine = ckeys[i];
    int higher = 0;
    for (int j = 0; j < M; ++j) higher += (ckeys[j] > mine) ? 1 : 0;
    if (higher < NNEG) {
      const int col = DCAT - 1 - (int)(mine & 0x3FFFull);
      acc += softplus_(prow[col]);        // negative term: softplus(x)
    }
  }

  // Block reduction -> one atomic per block.
  for (int off = 32; off > 0; off >>= 1) acc += __shfl_down(acc, off, 64);
  if ((tid & 63) == 0) wsum[tid >> 6] = acc;
  __syncthreads();
  if (tid == 0) {
    float s = 0.f;
    #pragma unroll
    for (int w = 0; w < BLK / 64; ++w) s += wsum[w];
    atomicAdd(out, s);
  }
}

extern "C" void kernel_launch(void* const* d_in, const int* in_sizes, int n_in,
                              void* d_out, int out_size, void* d_ws, size_t ws_size,
                              hipStream_t stream) {
  const float* pred   = (const float*)d_in[0];
  const float* target = (const float*)d_in[1];
  // d_in[2] = k (int scalar) — compile-time constant 8 in this problem.
  float* out = (float*)d_out;
  hipMemsetAsync(out, 0, sizeof(float), stream);
  t2l2_kernel<<<dim3(NROWS), dim3(BLK), 0, stream>>>(pred, target, out);
}